// Round 2
// baseline (1028.697 us; speedup 1.0000x reference)
//
#include <hip/hip_runtime.h>

// MSE-to-10-templates argmin over 262144 28x28 fp32 images.
// Memory-bound: 822 MB read @ ~6.3 TB/s => ~131 us floor.
// fp64 accumulation of cross terms so argmin matches a high-precision
// reference (index output, any flip = fail).

#define IMG      784
#define CHUNKS   196      // float4 chunks per image
#define NT       10
#define BLOCK    256
#define WPB      4        // waves per block
#define IPW      8        // images per wave per outer iter (4 groups x 2 images)

typedef float f32x4 __attribute__((ext_vector_type(4)));

__global__ __launch_bounds__(BLOCK, 4) void mse_argmin_kernel(
    const float* __restrict__ x,
    const float* __restrict__ tmpl,
    float* __restrict__ out,
    int B)
{
    __shared__ __align__(16) float tl[NT * IMG];   // 31360 B templates fp32
    __shared__ double tsq[NT];

    const int tid = threadIdx.x;

    // Stage templates into LDS (coalesced).
    for (int i = tid; i < NT * IMG; i += BLOCK) tl[i] = tmpl[i];
    __syncthreads();

    const int lane = tid & 63;
    const int wave = tid >> 6;

    // Per-block ||t_j||^2 in fp64: wave w handles templates w, w+4, w+8.
    for (int j = wave; j < NT; j += WPB) {
        double s = 0.0;
        for (int p = lane; p < IMG; p += 64) {
            double v = (double)tl[j * IMG + p];
            s += v * v;
        }
        #pragma unroll
        for (int m = 32; m >= 1; m >>= 1) s += __shfl_xor(s, m);
        if (lane == 0) tsq[j] = s;
    }
    __syncthreads();

    const int g = lane >> 4;     // group 0..3 within wave
    const int k = lane & 15;     // lane within group

    const int gwave  = blockIdx.x * WPB + wave;
    const int nwaves = gridDim.x * WPB;

    const f32x4* tl4 = (const f32x4*)tl;

    for (long long base = (long long)gwave * IPW; base < (long long)B;
         base += (long long)nwaves * IPW) {
        const long long i0 = base + 2 * g;
        const long long i1 = i0 + 1;
        const bool v0 = i0 < (long long)B;
        const bool v1 = i1 < (long long)B;
        const f32x4* x0 = (const f32x4*)(x + (v0 ? i0 : 0) * (long long)IMG);
        const f32x4* x1 = (const f32x4*)(x + (v1 ? i1 : 0) * (long long)IMG);

        double acc0[NT], acc1[NT];
        #pragma unroll
        for (int j = 0; j < NT; ++j) { acc0[j] = 0.0; acc1[j] = 0.0; }

        // 12 uniform chunk iterations: chunk c = k + 16*i, c in [0,192).
        #pragma unroll 2
        for (int i = 0; i < 12; ++i) {
            const int c = k + 16 * i;
            const f32x4 a = __builtin_nontemporal_load(&x0[c]);
            const f32x4 b = __builtin_nontemporal_load(&x1[c]);
            const double ax = a.x, ay = a.y, az = a.z, aw = a.w;
            const double bx = b.x, by = b.y, bz = b.z, bw = b.w;
            #pragma unroll
            for (int j = 0; j < NT; ++j) {
                const f32x4 tv = tl4[j * CHUNKS + c];
                const double tx = tv.x, ty = tv.y, tz = tv.z, tw = tv.w;
                acc0[j] = fma(aw, tw, fma(az, tz, fma(ay, ty, fma(ax, tx, acc0[j]))));
                acc1[j] = fma(bw, tw, fma(bz, tz, fma(by, ty, fma(bx, tx, acc1[j]))));
            }
        }
        // Tail: chunks 192..195 handled by lanes k<4.
        if (k < 4) {
            const int c = 192 + k;
            const f32x4 a = __builtin_nontemporal_load(&x0[c]);
            const f32x4 b = __builtin_nontemporal_load(&x1[c]);
            const double ax = a.x, ay = a.y, az = a.z, aw = a.w;
            const double bx = b.x, by = b.y, bz = b.z, bw = b.w;
            #pragma unroll
            for (int j = 0; j < NT; ++j) {
                const f32x4 tv = tl4[j * CHUNKS + c];
                const double tx = tv.x, ty = tv.y, tz = tv.z, tw = tv.w;
                acc0[j] = fma(aw, tw, fma(az, tz, fma(ay, ty, fma(ax, tx, acc0[j]))));
                acc1[j] = fma(bw, tw, fma(bz, tz, fma(by, ty, fma(bx, tx, acc1[j]))));
            }
        }

        // Group-of-16 xor-butterfly reduction (all 16 lanes end with full sums).
        #pragma unroll
        for (int m = 1; m <= 8; m <<= 1) {
            #pragma unroll
            for (int j = 0; j < NT; ++j) {
                acc0[j] += __shfl_xor(acc0[j], m);
                acc1[j] += __shfl_xor(acc1[j], m);
            }
        }

        // argmin_j (tsq_j - 2*cross_j); strict '<' keeps first-min (np tiebreak).
        if (k == 0 && v0) {
            double best = tsq[0] - 2.0 * acc0[0];
            int bi = 0;
            #pragma unroll
            for (int j = 1; j < NT; ++j) {
                const double d = tsq[j] - 2.0 * acc0[j];
                if (d < best) { best = d; bi = j; }
            }
            out[i0] = (float)bi;
        }
        if (k == 1 && v1) {
            double best = tsq[0] - 2.0 * acc1[0];
            int bi = 0;
            #pragma unroll
            for (int j = 1; j < NT; ++j) {
                const double d = tsq[j] - 2.0 * acc1[j];
                if (d < best) { best = d; bi = j; }
            }
            out[i1] = (float)bi;
        }
    }
}

extern "C" void kernel_launch(void* const* d_in, const int* in_sizes, int n_in,
                              void* d_out, int out_size, void* d_ws, size_t ws_size,
                              hipStream_t stream) {
    const float* x    = (const float*)d_in[0];
    const float* tmpl = (const float*)d_in[1];
    float* out        = (float*)d_out;
    const int B = in_sizes[0] / IMG;   // 262144

    // 1024 blocks x 4 waves = 4096 waves; 8 images per wave-iter => 8 outer iters.
    mse_argmin_kernel<<<1024, BLOCK, 0, stream>>>(x, tmpl, out, B);
}